// Round 16
// baseline (1029.608 us; speedup 1.0000x reference)
//
#include <hip/hip_runtime.h>
#include <hip/hip_fp16.h>
#include <cstdint>
#include <cstddef>

#define HIDC   64
#define NGAUSS 50
#define NLAYER 3
#define TGRID  8192            // nearest-neighbor grid; d-err <= 6.1e-4; 1MB/layer fp16
#define BSTRIDE 128            // dst nodes per bucket
#define MAXBUCK 1024           // supports N <= 131072
#define CHUNK_E 6656           // edges per partition chunk (stage fits 64KB LDS)
#define CUTOFF_F 10.0f
#define LOG2_C 0.69314718055994530942f

__device__ __forceinline__ float sspf(float v) {
  return fmaxf(v, 0.0f) + log1pf(expf(-fabsf(v))) - LOG2_C;
}

// ---------------------------------------------------------------------------
// Per-layer fp16 lookup tables T_l(g,j) = [ssp(rbf(d)@w1+b1)@w2+b2]_j * C(d)
// ---------------------------------------------------------------------------
__global__ __launch_bounds__(64) void build_table_k(
    const float* __restrict__ mlp_w1, const float* __restrict__ mlp_b1,
    const float* __restrict__ mlp_w2, const float* __restrict__ mlp_b2,
    __half* __restrict__ tabh) {
  int pid = blockIdx.x;              // l*TGRID + g
  int l = pid / TGRID;
  int g = pid - l * TGRID;
  int j = threadIdx.x;
  float d = (float)g * (CUTOFF_F / (float)(TGRID - 1));
  __shared__ float rbf_s[NGAUSS];
  __shared__ float hid_s[HIDC];
  const float delta = CUTOFF_F / (float)(NGAUSS - 1);
  const float coeff = -0.5f / (delta * delta);
  if (j < NGAUSS) {
    float t = d - (float)j * delta;
    rbf_s[j] = expf(coeff * t * t);
  }
  __syncthreads();
  const float* w1 = mlp_w1 + (size_t)l * NGAUSS * HIDC;
  float acc = mlp_b1[l * HIDC + j];
#pragma unroll
  for (int k = 0; k < NGAUSS; ++k) acc = fmaf(rbf_s[k], w1[k * HIDC + j], acc);
  hid_s[j] = sspf(acc);
  __syncthreads();
  const float* w2 = mlp_w2 + (size_t)l * HIDC * HIDC;
  float acc2 = mlp_b2[l * HIDC + j];
#pragma unroll
  for (int m = 0; m < HIDC; ++m) acc2 = fmaf(hid_s[m], w2[m * HIDC + j], acc2);
  float C = 0.5f * (cosf(d * (3.14159265358979323846f / CUTOFF_F)) + 1.0f);
  tabh[(size_t)pid * HIDC + j] = __float2half(acc2 * C);
}

// ---------------------------------------------------------------------------
// Zero-global-atomic chunked partition into bucket regions
// ---------------------------------------------------------------------------
__global__ __launch_bounds__(256) void chist_k(
    const int* __restrict__ edst, int* __restrict__ chunk_hist,
    int E, int nbuck) {
  __shared__ int cnt[MAXBUCK];
  for (int i = threadIdx.x; i < MAXBUCK; i += 256) cnt[i] = 0;
  __syncthreads();
  int c = blockIdx.x;
  int e0 = c * CHUNK_E;
  int e1 = e0 + CHUNK_E; if (e1 > E) e1 = E;
  for (int e = e0 + threadIdx.x; e < e1; e += 256)
    atomicAdd(&cnt[edst[e] >> 7], 1);
  __syncthreads();
  for (int i = threadIdx.x; i < nbuck; i += 256)
    chunk_hist[c * MAXBUCK + i] = cnt[i];
}

__global__ __launch_bounds__(256) void csum_k(
    const int* __restrict__ chunk_hist, int* __restrict__ bcnt,
    int nchunk, int nbuck) {
  int b = blockIdx.x * 256 + threadIdx.x;
  if (b >= nbuck) return;
  int s = 0;
  for (int c = 0; c < nchunk; ++c) s += chunk_hist[c * MAXBUCK + b];
  bcnt[b] = s;
}

__global__ __launch_bounds__(256) void bscan_k(
    const int* __restrict__ bcnt, int* __restrict__ boff, int nbuck) {
  __shared__ int sbuf[2][256];
  int tid = threadIdx.x;
  int base = tid * 4;
  int v0 = (base + 0 < nbuck) ? bcnt[base + 0] : 0;
  int v1 = (base + 1 < nbuck) ? bcnt[base + 1] : 0;
  int v2 = (base + 2 < nbuck) ? bcnt[base + 2] : 0;
  int v3 = (base + 3 < nbuck) ? bcnt[base + 3] : 0;
  int p0 = v0, p1 = p0 + v1, p2 = p1 + v2, p3 = p2 + v3;
  int pout = 0;
  sbuf[0][tid] = p3;
  __syncthreads();
  for (int off = 1; off < 256; off <<= 1) {
    int pin = pout; pout ^= 1;
    int v = sbuf[pin][tid];
    if (tid >= off) v += sbuf[pin][tid - off];
    sbuf[pout][tid] = v;
    __syncthreads();
  }
  int texc = sbuf[pout][tid] - p3;
  if (base + 0 < nbuck) boff[base + 0] = texc;
  if (base + 1 < nbuck) boff[base + 1] = texc + p0;
  if (base + 2 < nbuck) boff[base + 2] = texc + p1;
  if (base + 3 < nbuck) boff[base + 3] = texc + p2;
}

__global__ __launch_bounds__(256) void cbase_k(
    const int* __restrict__ chunk_hist, const int* __restrict__ boff,
    int* __restrict__ chunk_base, int nchunk) {
  __shared__ int sbuf[2][256];
  int b = blockIdx.x;
  int tid = threadIdx.x;
  int carry = 0;
  for (int t0 = 0; t0 < nchunk; t0 += 256) {
    int t = t0 + tid;
    int v = (t < nchunk) ? chunk_hist[(size_t)t * MAXBUCK + b] : 0;
    int pout = 0;
    sbuf[0][tid] = v;
    __syncthreads();
    for (int off = 1; off < 256; off <<= 1) {
      int pin = pout; pout ^= 1;
      int s = sbuf[pin][tid];
      if (tid >= off) s += sbuf[pin][tid - off];
      sbuf[pout][tid] = s;
      __syncthreads();
    }
    if (t < nchunk)
      chunk_base[(size_t)t * MAXBUCK + b] = boff[b] + carry + sbuf[pout][tid] - v;
    carry += sbuf[pout][255];
    __syncthreads();
  }
}

// LDS-staged scatter: stage chunk at local-CSR positions, burst copy-out.
__global__ __launch_bounds__(256) void cstage_k(
    const int* __restrict__ ei, const float* __restrict__ pos,
    const int* __restrict__ chunk_hist, const int* __restrict__ chunk_base,
    int2* __restrict__ er, int E, int nbuck) {
  __shared__ int2 stage[CHUNK_E];     // 53248 B
  __shared__ int loff[MAXBUCK];       // 4096 B
  __shared__ int lcur[MAXBUCK];       // 4096 B
  __shared__ int sbuf[2][256];        // 2048 B
  int c = blockIdx.x;
  int tid = threadIdx.x;
  const int* hrow = chunk_hist + (size_t)c * MAXBUCK;
  int base4 = tid * 4;
  int v0 = (base4 + 0 < nbuck) ? hrow[base4 + 0] : 0;
  int v1 = (base4 + 1 < nbuck) ? hrow[base4 + 1] : 0;
  int v2 = (base4 + 2 < nbuck) ? hrow[base4 + 2] : 0;
  int v3 = (base4 + 3 < nbuck) ? hrow[base4 + 3] : 0;
  int p0 = v0, p1 = p0 + v1, p2 = p1 + v2, p3 = p2 + v3;
  int pout = 0;
  sbuf[0][tid] = p3;
  __syncthreads();
  for (int off = 1; off < 256; off <<= 1) {
    int pin = pout; pout ^= 1;
    int v = sbuf[pin][tid];
    if (tid >= off) v += sbuf[pin][tid - off];
    sbuf[pout][tid] = v;
    __syncthreads();
  }
  int texc = sbuf[pout][tid] - p3;
  if (base4 + 0 < MAXBUCK) { loff[base4 + 0] = texc;      lcur[base4 + 0] = texc; }
  if (base4 + 1 < MAXBUCK) { loff[base4 + 1] = texc + p0; lcur[base4 + 1] = texc + p0; }
  if (base4 + 2 < MAXBUCK) { loff[base4 + 2] = texc + p1; lcur[base4 + 2] = texc + p1; }
  if (base4 + 3 < MAXBUCK) { loff[base4 + 3] = texc + p2; lcur[base4 + 3] = texc + p2; }
  __syncthreads();
  int e0 = c * CHUNK_E;
  int e1 = e0 + CHUNK_E; if (e1 > E) e1 = E;
  for (int e = e0 + tid; e < e1; e += 256) {
    int s = ei[e], t = ei[E + e];
    float dx = pos[3 * s + 0] - pos[3 * t + 0];
    float dy = pos[3 * s + 1] - pos[3 * t + 1];
    float dz = pos[3 * s + 2] - pos[3 * t + 2];
    float d = sqrtf(fmaf(dx, dx, fmaf(dy, dy, dz * dz)));
    float u = d * ((float)(TGRID - 1) / CUTOFF_F);
    int i0 = (int)(u + 0.5f);          // nearest
    if (i0 > TGRID - 1) i0 = TGRID - 1;
    int b = t >> 7;
    int dl = t & 127;
    int p = atomicAdd(&lcur[b], 1);
    stage[p] = make_int2(s | (dl << 20), i0);
  }
  __syncthreads();
  int w = tid >> 6;
  int lane = tid & 63;
  for (int b = w; b < nbuck; b += 4) {
    int st = loff[b];
    int cn = lcur[b] - st;
    int gb = chunk_base[(size_t)c * MAXBUCK + b];
    for (int i = lane; i < cn; i += 64)
      er[gb + i] = stage[st + i];
  }
}

// One WG per bucket: self-computed node-CSR (degrees + scan -> rs), place.
// Final records packed to 4 B: src(17) | i0(15)<<17.
__global__ __launch_bounds__(256) void bsort_k(
    const int* __restrict__ boff, const int* __restrict__ bcnt,
    const int2* __restrict__ er, int* __restrict__ er2,
    int* __restrict__ rs, int n) {
  __shared__ int dcnt[BSTRIDE];
  __shared__ int lcur[BSTRIDE];
  __shared__ int sc[2][BSTRIDE];
  int b = blockIdx.x;
  int node0 = b << 7;
  int nn = n - node0; if (nn > BSTRIDE) nn = BSTRIDE;
  int tid = threadIdx.x;
  if (tid < BSTRIDE) dcnt[tid] = 0;
  __syncthreads();
  int base = boff[b];
  int cnt = bcnt[b];
  for (int r = tid; r < cnt; r += 256)
    atomicAdd(&dcnt[(unsigned)er[base + r].x >> 20], 1);
  __syncthreads();
  int pout = 0;
  if (tid < BSTRIDE) sc[0][tid] = dcnt[tid];
  __syncthreads();
  for (int off = 1; off < BSTRIDE; off <<= 1) {
    int pin = pout; pout ^= 1;
    if (tid < BSTRIDE) {
      int v = sc[pin][tid];
      if (tid >= off) v += sc[pin][tid - off];
      sc[pout][tid] = v;
    }
    __syncthreads();
  }
  if (tid < BSTRIDE) {
    int start = base + sc[pout][tid] - dcnt[tid];
    lcur[tid] = start;
    if (tid < nn) rs[node0 + tid] = start;
  }
  if (tid == 0 && b == gridDim.x - 1) rs[n] = base + cnt;
  __syncthreads();
  for (int r = tid; r < cnt; r += 256) {
    int2 rec = er[base + r];
    int dl = (unsigned)rec.x >> 20;
    int p = atomicAdd(&lcur[dl], 1);
    er2[p] = (rec.x & 0x1FFFF) | (rec.y << 17);
  }
}

// h = emb[z]
__global__ __launch_bounds__(256) void init_h_k(
    const int* __restrict__ z, const float* __restrict__ emb,
    float* __restrict__ h, int n64) {
  int i = blockIdx.x * blockDim.x + threadIdx.x;
  if (i >= n64) return;
  h[i] = emb[(z[i >> 6] << 6) | (i & 63)];
}

// x = half(h @ W) (no bias), fp16 output for the gather
__global__ __launch_bounds__(256, 2) void node_lin_k(
    const float* __restrict__ h, const float* __restrict__ W,
    __half* __restrict__ x, int n) {
  int node = blockIdx.x * 256 + threadIdx.x;
  if (node >= n) return;
  const float* row = h + ((size_t)node << 6);
  float acc[HIDC];
#pragma unroll
  for (int j = 0; j < HIDC; ++j) acc[j] = 0.0f;
  for (int k = 0; k < HIDC; k += 4) {
    float4 rv = *(const float4*)(row + k);
    const float* w0 = W + (k + 0) * HIDC;
    const float* w1 = W + (k + 1) * HIDC;
    const float* w2 = W + (k + 2) * HIDC;
    const float* w3 = W + (k + 3) * HIDC;
#pragma unroll
    for (int j = 0; j < HIDC; ++j) {
      acc[j] = fmaf(rv.x, w0[j], acc[j]);
      acc[j] = fmaf(rv.y, w1[j], acc[j]);
      acc[j] = fmaf(rv.z, w2[j], acc[j]);
      acc[j] = fmaf(rv.w, w3[j], acc[j]);
    }
  }
  __half2* xr = (__half2*)(x + ((size_t)node << 6));
#pragma unroll
  for (int j = 0; j < HIDC; j += 2)
    xr[j >> 1] = __floats2half2_rn(acc[j], acc[j + 1]);
}

// THE HOT KERNEL. One wave per dst node, unroll x8 (16 outstanding loads),
// register accumulator; 4-byte records, nearest-neighbor fp16 table, fp16 x.
__global__ __launch_bounds__(256) void gather_k(
    const int* __restrict__ rs, const int* __restrict__ er,
    const __half* __restrict__ tabh, const __half* __restrict__ x,
    float* __restrict__ agg, int n) {
  int j = threadIdx.x & 63;
  int node = (blockIdx.x * 256 + threadIdx.x) >> 6;
  if (node >= n) return;
  int beg = __builtin_amdgcn_readfirstlane(rs[node]);
  int end = __builtin_amdgcn_readfirstlane(rs[node + 1]);
  float acc = 0.0f;
  int k = beg;
  for (; k + 8 <= end; k += 8) {
    int r0 = er[k + 0];
    int r1 = er[k + 1];
    int r2 = er[k + 2];
    int r3 = er[k + 3];
    int r4 = er[k + 4];
    int r5 = er[k + 5];
    int r6 = er[k + 6];
    int r7 = er[k + 7];
    float t0 = __half2float(tabh[(((size_t)((unsigned)r0 >> 17)) << 6) + j]);
    float t1 = __half2float(tabh[(((size_t)((unsigned)r1 >> 17)) << 6) + j]);
    float t2 = __half2float(tabh[(((size_t)((unsigned)r2 >> 17)) << 6) + j]);
    float t3 = __half2float(tabh[(((size_t)((unsigned)r3 >> 17)) << 6) + j]);
    float t4 = __half2float(tabh[(((size_t)((unsigned)r4 >> 17)) << 6) + j]);
    float t5 = __half2float(tabh[(((size_t)((unsigned)r5 >> 17)) << 6) + j]);
    float t6 = __half2float(tabh[(((size_t)((unsigned)r6 >> 17)) << 6) + j]);
    float t7 = __half2float(tabh[(((size_t)((unsigned)r7 >> 17)) << 6) + j]);
    float x0 = __half2float(x[((size_t)(r0 & 0x1FFFF) << 6) + j]);
    float x1 = __half2float(x[((size_t)(r1 & 0x1FFFF) << 6) + j]);
    float x2 = __half2float(x[((size_t)(r2 & 0x1FFFF) << 6) + j]);
    float x3 = __half2float(x[((size_t)(r3 & 0x1FFFF) << 6) + j]);
    float x4 = __half2float(x[((size_t)(r4 & 0x1FFFF) << 6) + j]);
    float x5 = __half2float(x[((size_t)(r5 & 0x1FFFF) << 6) + j]);
    float x6 = __half2float(x[((size_t)(r6 & 0x1FFFF) << 6) + j]);
    float x7 = __half2float(x[((size_t)(r7 & 0x1FFFF) << 6) + j]);
    acc = fmaf(x0, t0, acc);
    acc = fmaf(x1, t1, acc);
    acc = fmaf(x2, t2, acc);
    acc = fmaf(x3, t3, acc);
    acc = fmaf(x4, t4, acc);
    acc = fmaf(x5, t5, acc);
    acc = fmaf(x6, t6, acc);
    acc = fmaf(x7, t7, acc);
  }
  for (; k < end; ++k) {
    int r = er[k];
    float t = __half2float(tabh[(((size_t)((unsigned)r >> 17)) << 6) + j]);
    float xv = __half2float(x[((size_t)(r & 0x1FFFF) << 6) + j]);
    acc = fmaf(xv, t, acc);
  }
  agg[((size_t)node << 6) + j] = acc;
}

// agg = ssp(agg @ W2 + b2)   (in-place; fp32)
__global__ __launch_bounds__(256, 2) void update1_k(
    float* __restrict__ agg, const float* __restrict__ W2,
    const float* __restrict__ b2, int n) {
  int node = blockIdx.x * 256 + threadIdx.x;
  if (node >= n) return;
  float* row = agg + ((size_t)node << 6);
  float acc[HIDC];
#pragma unroll
  for (int j = 0; j < HIDC; ++j) acc[j] = b2[j];
  for (int k = 0; k < HIDC; k += 4) {
    float4 rv = *(const float4*)(row + k);
    const float* w0 = W2 + (k + 0) * HIDC;
    const float* w1 = W2 + (k + 1) * HIDC;
    const float* w2 = W2 + (k + 2) * HIDC;
    const float* w3 = W2 + (k + 3) * HIDC;
#pragma unroll
    for (int j = 0; j < HIDC; ++j) {
      acc[j] = fmaf(rv.x, w0[j], acc[j]);
      acc[j] = fmaf(rv.y, w1[j], acc[j]);
      acc[j] = fmaf(rv.z, w2[j], acc[j]);
      acc[j] = fmaf(rv.w, w3[j], acc[j]);
    }
  }
#pragma unroll
  for (int j = 0; j < HIDC; j += 4) {
    float4 o = make_float4(sspf(acc[j]), sspf(acc[j + 1]),
                           sspf(acc[j + 2]), sspf(acc[j + 3]));
    *(float4*)(row + j) = o;
  }
}

// h += agg @ W3 + b3   (fp32)
__global__ __launch_bounds__(256, 2) void update2_k(
    const float* __restrict__ agg, const float* __restrict__ W3,
    const float* __restrict__ b3, float* __restrict__ h, int n) {
  int node = blockIdx.x * 256 + threadIdx.x;
  if (node >= n) return;
  const float* row = agg + ((size_t)node << 6);
  float acc[HIDC];
#pragma unroll
  for (int j = 0; j < HIDC; ++j) acc[j] = b3[j];
  for (int k = 0; k < HIDC; k += 4) {
    float4 rv = *(const float4*)(row + k);
    const float* w0 = W3 + (k + 0) * HIDC;
    const float* w1 = W3 + (k + 1) * HIDC;
    const float* w2 = W3 + (k + 2) * HIDC;
    const float* w3 = W3 + (k + 3) * HIDC;
#pragma unroll
    for (int j = 0; j < HIDC; ++j) {
      acc[j] = fmaf(rv.x, w0[j], acc[j]);
      acc[j] = fmaf(rv.y, w1[j], acc[j]);
      acc[j] = fmaf(rv.z, w2[j], acc[j]);
      acc[j] = fmaf(rv.w, w3[j], acc[j]);
    }
  }
  float* hr = h + ((size_t)node << 6);
#pragma unroll
  for (int j = 0; j < HIDC; j += 4) {
    float4 hv = *(float4*)(hr + j);
    hv.x += acc[j]; hv.y += acc[j + 1];
    hv.z += acc[j + 2]; hv.w += acc[j + 3];
    *(float4*)(hr + j) = hv;
  }
}

// per-atom output MLP + segmented wave reduce (batch sorted) + atomic
__global__ __launch_bounds__(256, 2) void out_kernel_k(
    const float* __restrict__ h, const int* __restrict__ batch,
    const float* __restrict__ ow1, const float* __restrict__ ob1,
    const float* __restrict__ ow2, const float* __restrict__ ob2,
    float* __restrict__ outg, int n) {
  int node = blockIdx.x * 256 + threadIdx.x;
  int lane = threadIdx.x & 63;
  bool valid = node < n;
  int b = batch[valid ? node : (n - 1)];
  float s = 0.0f;
  if (valid) {
    const float* row = h + ((size_t)node << 6);
    float acc[32];
#pragma unroll
    for (int j = 0; j < 32; ++j) acc[j] = ob1[j];
    for (int k = 0; k < HIDC; k += 4) {
      float4 rv = *(const float4*)(row + k);
      const float* w0 = ow1 + (k + 0) * 32;
      const float* w1 = ow1 + (k + 1) * 32;
      const float* w2 = ow1 + (k + 2) * 32;
      const float* w3 = ow1 + (k + 3) * 32;
#pragma unroll
      for (int j = 0; j < 32; ++j) {
        acc[j] = fmaf(rv.x, w0[j], acc[j]);
        acc[j] = fmaf(rv.y, w1[j], acc[j]);
        acc[j] = fmaf(rv.z, w2[j], acc[j]);
        acc[j] = fmaf(rv.w, w3[j], acc[j]);
      }
    }
    s = ob2[0];
#pragma unroll
    for (int j = 0; j < 32; ++j) s = fmaf(sspf(acc[j]), ow2[j], s);
  }
#pragma unroll
  for (int off = 1; off < 64; off <<= 1) {
    float so = __shfl_down(s, off);
    int bo = __shfl_down(b, off);
    if (lane + off < 64 && bo == b) s += so;
  }
  int bprev = __shfl_up(b, 1);
  bool head = (lane == 0) || (bprev != b);
  if (head && valid) unsafeAtomicAdd(&outg[b], s);
}

__global__ __launch_bounds__(256) void final_k(
    const float* __restrict__ outg, const float* __restrict__ fw,
    const float* __restrict__ fb, float* __restrict__ out, int g) {
  int i = blockIdx.x * blockDim.x + threadIdx.x;
  if (i < g) out[i] = fmaf(outg[i], fw[0], fb[0]);
}

extern "C" void kernel_launch(void* const* d_in, const int* in_sizes, int n_in,
                              void* d_out, int out_size, void* d_ws, size_t ws_size,
                              hipStream_t stream) {
  const int*   z      = (const int*)d_in[0];
  const float* pos    = (const float*)d_in[1];
  const int*   batch  = (const int*)d_in[2];
  const int*   ei     = (const int*)d_in[3];
  const float* emb    = (const float*)d_in[4];
  const float* out_w1 = (const float*)d_in[5];
  const float* out_b1 = (const float*)d_in[6];
  const float* out_w2 = (const float*)d_in[7];
  const float* out_b2 = (const float*)d_in[8];
  const float* fin_w  = (const float*)d_in[9];
  const float* fin_b  = (const float*)d_in[10];
  const float* mlp_w1 = (const float*)d_in[11];
  const float* mlp_b1 = (const float*)d_in[12];
  const float* mlp_w2 = (const float*)d_in[13];
  const float* mlp_b2 = (const float*)d_in[14];
  const float* cf1    = (const float*)d_in[15];
  const float* cf2    = (const float*)d_in[16];
  const float* cf2b   = (const float*)d_in[17];
  const float* intw   = (const float*)d_in[18];
  const float* intb   = (const float*)d_in[19];

  const int N = in_sizes[0];
  const int E = in_sizes[3] / 2;
  const int G = out_size;
  const int NBUCK = (N + BSTRIDE - 1) / BSTRIDE;
  const int NCHUNK = (E + CHUNK_E - 1) / CHUNK_E;
  const int TPB = (N + 255) / 256;

  char* wsb = (char*)d_ws;
  size_t off = 0;
  auto alloc = [&](size_t bytes) { char* p = wsb + off; off += (bytes + 255) & ~(size_t)255; return p; };
  float*   h     = (float*)alloc((size_t)N * HIDC * sizeof(float));
  __half*  x     = (__half*)alloc((size_t)N * HIDC * sizeof(__half));
  float*   agg   = (float*)alloc((size_t)N * HIDC * sizeof(float));
  __half*  tabh  = (__half*)alloc((size_t)NLAYER * TGRID * HIDC * sizeof(__half));
  int2*    er    = (int2*)alloc((size_t)E * sizeof(int2));   // bucket-ordered
  int*     er2   = (int*)alloc((size_t)E * sizeof(int));     // node-CSR, 4B packed
  int*     rs    = (int*)alloc((size_t)(N + 1) * sizeof(int));
  int*     bcnt  = (int*)alloc((size_t)MAXBUCK * sizeof(int));
  int*     boff  = (int*)alloc((size_t)MAXBUCK * sizeof(int));
  int*     chist = (int*)alloc((size_t)NCHUNK * MAXBUCK * sizeof(int));
  int*     cbase = (int*)alloc((size_t)NCHUNK * MAXBUCK * sizeof(int));
  float*   outg  = (float*)alloc((size_t)G * sizeof(float));

  build_table_k<<<dim3(NLAYER * TGRID), dim3(64), 0, stream>>>(
      mlp_w1, mlp_b1, mlp_w2, mlp_b2, tabh);
  hipMemsetAsync(outg, 0, (size_t)G * sizeof(float), stream);
  chist_k<<<dim3(NCHUNK), dim3(256), 0, stream>>>(ei + E, chist, E, NBUCK);
  csum_k<<<dim3((NBUCK + 255) / 256), dim3(256), 0, stream>>>(
      chist, bcnt, NCHUNK, NBUCK);
  bscan_k<<<dim3(1), dim3(256), 0, stream>>>(bcnt, boff, NBUCK);
  cbase_k<<<dim3(NBUCK), dim3(256), 0, stream>>>(chist, boff, cbase, NCHUNK);
  cstage_k<<<dim3(NCHUNK), dim3(256), 0, stream>>>(
      ei, pos, chist, cbase, er, E, NBUCK);
  bsort_k<<<dim3(NBUCK), dim3(256), 0, stream>>>(boff, bcnt, er, er2, rs, N);
  init_h_k<<<dim3((N * HIDC + 255) / 256), dim3(256), 0, stream>>>(z, emb, h, N * HIDC);

  const int gather_blocks = (N + 3) / 4;   // one wave per node
  for (int l = 0; l < NLAYER; ++l) {
    node_lin_k<<<dim3(TPB), dim3(256), 0, stream>>>(
        h, cf1 + (size_t)l * HIDC * HIDC, x, N);
    gather_k<<<dim3(gather_blocks), dim3(256), 0, stream>>>(
        rs, er2, tabh + (size_t)l * TGRID * HIDC, x, agg, N);
    update1_k<<<dim3(TPB), dim3(256), 0, stream>>>(
        agg, cf2 + (size_t)l * HIDC * HIDC, cf2b + l * HIDC, N);
    update2_k<<<dim3(TPB), dim3(256), 0, stream>>>(
        agg, intw + (size_t)l * HIDC * HIDC, intb + l * HIDC, h, N);
  }

  out_kernel_k<<<dim3(TPB), dim3(256), 0, stream>>>(
      h, batch, out_w1, out_b1, out_w2, out_b2, outg, N);
  final_k<<<dim3((G + 255) / 256), dim3(256), 0, stream>>>(
      outg, fin_w, fin_b, (float*)d_out, G);
}

// Round 17
// 945.317 us; speedup vs baseline: 1.0892x; 1.0892x over previous
//
#include <hip/hip_runtime.h>
#include <hip/hip_fp16.h>
#include <cstdint>
#include <cstddef>

#define HIDC   64
#define NGAUSS 50
#define NLAYER 3
#define TGRID  8192            // nearest-neighbor grid; d-err <= 6.1e-4; 1MB/layer fp16
#define BSTRIDE 128            // dst nodes per bucket
#define MAXBUCK 1024           // supports N <= 131072
#define CHUNK_E 6656           // edges per partition chunk (stage fits 64KB LDS)
#define CUTOFF_F 10.0f
#define LOG2_C 0.69314718055994530942f

__device__ __forceinline__ float sspf(float v) {
  return fmaxf(v, 0.0f) + log1pf(expf(-fabsf(v))) - LOG2_C;
}

// ---------------------------------------------------------------------------
// Per-layer fp16 lookup tables T_l(g,j) = [ssp(rbf(d)@w1+b1)@w2+b2]_j * C(d)
// ---------------------------------------------------------------------------
__global__ __launch_bounds__(64) void build_table_k(
    const float* __restrict__ mlp_w1, const float* __restrict__ mlp_b1,
    const float* __restrict__ mlp_w2, const float* __restrict__ mlp_b2,
    __half* __restrict__ tabh) {
  int pid = blockIdx.x;              // l*TGRID + g
  int l = pid / TGRID;
  int g = pid - l * TGRID;
  int j = threadIdx.x;
  float d = (float)g * (CUTOFF_F / (float)(TGRID - 1));
  __shared__ float rbf_s[NGAUSS];
  __shared__ float hid_s[HIDC];
  const float delta = CUTOFF_F / (float)(NGAUSS - 1);
  const float coeff = -0.5f / (delta * delta);
  if (j < NGAUSS) {
    float t = d - (float)j * delta;
    rbf_s[j] = expf(coeff * t * t);
  }
  __syncthreads();
  const float* w1 = mlp_w1 + (size_t)l * NGAUSS * HIDC;
  float acc = mlp_b1[l * HIDC + j];
#pragma unroll
  for (int k = 0; k < NGAUSS; ++k) acc = fmaf(rbf_s[k], w1[k * HIDC + j], acc);
  hid_s[j] = sspf(acc);
  __syncthreads();
  const float* w2 = mlp_w2 + (size_t)l * HIDC * HIDC;
  float acc2 = mlp_b2[l * HIDC + j];
#pragma unroll
  for (int m = 0; m < HIDC; ++m) acc2 = fmaf(hid_s[m], w2[m * HIDC + j], acc2);
  float C = 0.5f * (cosf(d * (3.14159265358979323846f / CUTOFF_F)) + 1.0f);
  tabh[(size_t)pid * HIDC + j] = __float2half(acc2 * C);
}

// ---------------------------------------------------------------------------
// Zero-global-atomic chunked partition into bucket regions
// ---------------------------------------------------------------------------
__global__ __launch_bounds__(256) void chist_k(
    const int* __restrict__ edst, int* __restrict__ chunk_hist,
    int E, int nbuck) {
  __shared__ int cnt[MAXBUCK];
  for (int i = threadIdx.x; i < MAXBUCK; i += 256) cnt[i] = 0;
  __syncthreads();
  int c = blockIdx.x;
  int e0 = c * CHUNK_E;
  int e1 = e0 + CHUNK_E; if (e1 > E) e1 = E;
  for (int e = e0 + threadIdx.x; e < e1; e += 256)
    atomicAdd(&cnt[edst[e] >> 7], 1);
  __syncthreads();
  for (int i = threadIdx.x; i < nbuck; i += 256)
    chunk_hist[c * MAXBUCK + i] = cnt[i];
}

__global__ __launch_bounds__(256) void csum_k(
    const int* __restrict__ chunk_hist, int* __restrict__ bcnt,
    int nchunk, int nbuck) {
  int b = blockIdx.x * 256 + threadIdx.x;
  if (b >= nbuck) return;
  int s = 0;
  for (int c = 0; c < nchunk; ++c) s += chunk_hist[c * MAXBUCK + b];
  bcnt[b] = s;
}

__global__ __launch_bounds__(256) void bscan_k(
    const int* __restrict__ bcnt, int* __restrict__ boff, int nbuck) {
  __shared__ int sbuf[2][256];
  int tid = threadIdx.x;
  int base = tid * 4;
  int v0 = (base + 0 < nbuck) ? bcnt[base + 0] : 0;
  int v1 = (base + 1 < nbuck) ? bcnt[base + 1] : 0;
  int v2 = (base + 2 < nbuck) ? bcnt[base + 2] : 0;
  int v3 = (base + 3 < nbuck) ? bcnt[base + 3] : 0;
  int p0 = v0, p1 = p0 + v1, p2 = p1 + v2, p3 = p2 + v3;
  int pout = 0;
  sbuf[0][tid] = p3;
  __syncthreads();
  for (int off = 1; off < 256; off <<= 1) {
    int pin = pout; pout ^= 1;
    int v = sbuf[pin][tid];
    if (tid >= off) v += sbuf[pin][tid - off];
    sbuf[pout][tid] = v;
    __syncthreads();
  }
  int texc = sbuf[pout][tid] - p3;
  if (base + 0 < nbuck) boff[base + 0] = texc;
  if (base + 1 < nbuck) boff[base + 1] = texc + p0;
  if (base + 2 < nbuck) boff[base + 2] = texc + p1;
  if (base + 3 < nbuck) boff[base + 3] = texc + p2;
}

__global__ __launch_bounds__(256) void cbase_k(
    const int* __restrict__ chunk_hist, const int* __restrict__ boff,
    int* __restrict__ chunk_base, int nchunk) {
  __shared__ int sbuf[2][256];
  int b = blockIdx.x;
  int tid = threadIdx.x;
  int carry = 0;
  for (int t0 = 0; t0 < nchunk; t0 += 256) {
    int t = t0 + tid;
    int v = (t < nchunk) ? chunk_hist[(size_t)t * MAXBUCK + b] : 0;
    int pout = 0;
    sbuf[0][tid] = v;
    __syncthreads();
    for (int off = 1; off < 256; off <<= 1) {
      int pin = pout; pout ^= 1;
      int s = sbuf[pin][tid];
      if (tid >= off) s += sbuf[pin][tid - off];
      sbuf[pout][tid] = s;
      __syncthreads();
    }
    if (t < nchunk)
      chunk_base[(size_t)t * MAXBUCK + b] = boff[b] + carry + sbuf[pout][tid] - v;
    carry += sbuf[pout][255];
    __syncthreads();
  }
}

// LDS-staged scatter: stage chunk at local-CSR positions, burst copy-out.
__global__ __launch_bounds__(256) void cstage_k(
    const int* __restrict__ ei, const float* __restrict__ pos,
    const int* __restrict__ chunk_hist, const int* __restrict__ chunk_base,
    int2* __restrict__ er, int E, int nbuck) {
  __shared__ int2 stage[CHUNK_E];     // 53248 B
  __shared__ int loff[MAXBUCK];       // 4096 B
  __shared__ int lcur[MAXBUCK];       // 4096 B
  __shared__ int sbuf[2][256];        // 2048 B
  int c = blockIdx.x;
  int tid = threadIdx.x;
  const int* hrow = chunk_hist + (size_t)c * MAXBUCK;
  int base4 = tid * 4;
  int v0 = (base4 + 0 < nbuck) ? hrow[base4 + 0] : 0;
  int v1 = (base4 + 1 < nbuck) ? hrow[base4 + 1] : 0;
  int v2 = (base4 + 2 < nbuck) ? hrow[base4 + 2] : 0;
  int v3 = (base4 + 3 < nbuck) ? hrow[base4 + 3] : 0;
  int p0 = v0, p1 = p0 + v1, p2 = p1 + v2, p3 = p2 + v3;
  int pout = 0;
  sbuf[0][tid] = p3;
  __syncthreads();
  for (int off = 1; off < 256; off <<= 1) {
    int pin = pout; pout ^= 1;
    int v = sbuf[pin][tid];
    if (tid >= off) v += sbuf[pin][tid - off];
    sbuf[pout][tid] = v;
    __syncthreads();
  }
  int texc = sbuf[pout][tid] - p3;
  if (base4 + 0 < MAXBUCK) { loff[base4 + 0] = texc;      lcur[base4 + 0] = texc; }
  if (base4 + 1 < MAXBUCK) { loff[base4 + 1] = texc + p0; lcur[base4 + 1] = texc + p0; }
  if (base4 + 2 < MAXBUCK) { loff[base4 + 2] = texc + p1; lcur[base4 + 2] = texc + p1; }
  if (base4 + 3 < MAXBUCK) { loff[base4 + 3] = texc + p2; lcur[base4 + 3] = texc + p2; }
  __syncthreads();
  int e0 = c * CHUNK_E;
  int e1 = e0 + CHUNK_E; if (e1 > E) e1 = E;
  for (int e = e0 + tid; e < e1; e += 256) {
    int s = ei[e], t = ei[E + e];
    float dx = pos[3 * s + 0] - pos[3 * t + 0];
    float dy = pos[3 * s + 1] - pos[3 * t + 1];
    float dz = pos[3 * s + 2] - pos[3 * t + 2];
    float d = sqrtf(fmaf(dx, dx, fmaf(dy, dy, dz * dz)));
    float u = d * ((float)(TGRID - 1) / CUTOFF_F);
    int i0 = (int)(u + 0.5f);          // nearest
    if (i0 > TGRID - 1) i0 = TGRID - 1;
    int b = t >> 7;
    int dl = t & 127;
    int p = atomicAdd(&lcur[b], 1);
    stage[p] = make_int2(s | (dl << 20), i0);
  }
  __syncthreads();
  int w = tid >> 6;
  int lane = tid & 63;
  for (int b = w; b < nbuck; b += 4) {
    int st = loff[b];
    int cn = lcur[b] - st;
    int gb = chunk_base[(size_t)c * MAXBUCK + b];
    for (int i = lane; i < cn; i += 64)
      er[gb + i] = stage[st + i];
  }
}

// One WG per bucket: self-computed node-CSR (degrees + scan -> rs), place.
// Final records packed to 4 B: src(17) | i0(15)<<17.
__global__ __launch_bounds__(256) void bsort_k(
    const int* __restrict__ boff, const int* __restrict__ bcnt,
    const int2* __restrict__ er, int* __restrict__ er2,
    int* __restrict__ rs, int n) {
  __shared__ int dcnt[BSTRIDE];
  __shared__ int lcur[BSTRIDE];
  __shared__ int sc[2][BSTRIDE];
  int b = blockIdx.x;
  int node0 = b << 7;
  int nn = n - node0; if (nn > BSTRIDE) nn = BSTRIDE;
  int tid = threadIdx.x;
  if (tid < BSTRIDE) dcnt[tid] = 0;
  __syncthreads();
  int base = boff[b];
  int cnt = bcnt[b];
  for (int r = tid; r < cnt; r += 256)
    atomicAdd(&dcnt[(unsigned)er[base + r].x >> 20], 1);
  __syncthreads();
  int pout = 0;
  if (tid < BSTRIDE) sc[0][tid] = dcnt[tid];
  __syncthreads();
  for (int off = 1; off < BSTRIDE; off <<= 1) {
    int pin = pout; pout ^= 1;
    if (tid < BSTRIDE) {
      int v = sc[pin][tid];
      if (tid >= off) v += sc[pin][tid - off];
      sc[pout][tid] = v;
    }
    __syncthreads();
  }
  if (tid < BSTRIDE) {
    int start = base + sc[pout][tid] - dcnt[tid];
    lcur[tid] = start;
    if (tid < nn) rs[node0 + tid] = start;
  }
  if (tid == 0 && b == gridDim.x - 1) rs[n] = base + cnt;
  __syncthreads();
  for (int r = tid; r < cnt; r += 256) {
    int2 rec = er[base + r];
    int dl = (unsigned)rec.x >> 20;
    int p = atomicAdd(&lcur[dl], 1);
    er2[p] = (rec.x & 0x1FFFF) | (rec.y << 17);
  }
}

// h = emb[z]
__global__ __launch_bounds__(256) void init_h_k(
    const int* __restrict__ z, const float* __restrict__ emb,
    float* __restrict__ h, int n64) {
  int i = blockIdx.x * blockDim.x + threadIdx.x;
  if (i >= n64) return;
  h[i] = emb[(z[i >> 6] << 6) | (i & 63)];
}

// ---------------------------------------------------------------------------
// Thread-per-node GEMMs, 32 output channels per pass (acc[32] ~= 45 VGPRs):
// structurally immune to the allocator's low-VGPR spill heuristic (R16: the
// 64-wide in-place variant spilled at VGPR_Count=52 -> 99 MB scratch WRITE).
// ---------------------------------------------------------------------------

// x = half(h @ W) (no bias), fp16 output for the gather
__global__ __launch_bounds__(256, 2) void node_lin_k(
    const float* __restrict__ h, const float* __restrict__ W,
    __half* __restrict__ x, int n) {
  int node = blockIdx.x * 256 + threadIdx.x;
  if (node >= n) return;
  const float* row = h + ((size_t)node << 6);
  __half2* xr = (__half2*)(x + ((size_t)node << 6));
#pragma unroll
  for (int half = 0; half < 2; ++half) {
    const float* Wh = W + half * 32;
    float acc[32];
#pragma unroll
    for (int j = 0; j < 32; ++j) acc[j] = 0.0f;
    for (int k = 0; k < HIDC; k += 4) {
      float4 rv = *(const float4*)(row + k);
      const float* w0 = Wh + (k + 0) * HIDC;
      const float* w1 = Wh + (k + 1) * HIDC;
      const float* w2 = Wh + (k + 2) * HIDC;
      const float* w3 = Wh + (k + 3) * HIDC;
#pragma unroll
      for (int j = 0; j < 32; ++j) {
        acc[j] = fmaf(rv.x, w0[j], acc[j]);
        acc[j] = fmaf(rv.y, w1[j], acc[j]);
        acc[j] = fmaf(rv.z, w2[j], acc[j]);
        acc[j] = fmaf(rv.w, w3[j], acc[j]);
      }
    }
#pragma unroll
    for (int j = 0; j < 32; j += 2)
      xr[(half * 32 + j) >> 1] = __floats2half2_rn(acc[j], acc[j + 1]);
  }
}

// t = ssp(agg @ W2 + b2)  (separate output buffer — no in-place aliasing)
__global__ __launch_bounds__(256, 2) void update1_k(
    const float* __restrict__ agg, const float* __restrict__ W2,
    const float* __restrict__ b2, float* __restrict__ t, int n) {
  int node = blockIdx.x * 256 + threadIdx.x;
  if (node >= n) return;
  const float* row = agg + ((size_t)node << 6);
  float* tr = t + ((size_t)node << 6);
#pragma unroll
  for (int half = 0; half < 2; ++half) {
    const float* Wh = W2 + half * 32;
    float acc[32];
#pragma unroll
    for (int j = 0; j < 32; ++j) acc[j] = b2[half * 32 + j];
    for (int k = 0; k < HIDC; k += 4) {
      float4 rv = *(const float4*)(row + k);
      const float* w0 = Wh + (k + 0) * HIDC;
      const float* w1 = Wh + (k + 1) * HIDC;
      const float* w2 = Wh + (k + 2) * HIDC;
      const float* w3 = Wh + (k + 3) * HIDC;
#pragma unroll
      for (int j = 0; j < 32; ++j) {
        acc[j] = fmaf(rv.x, w0[j], acc[j]);
        acc[j] = fmaf(rv.y, w1[j], acc[j]);
        acc[j] = fmaf(rv.z, w2[j], acc[j]);
        acc[j] = fmaf(rv.w, w3[j], acc[j]);
      }
    }
#pragma unroll
    for (int j = 0; j < 32; j += 4) {
      float4 o = make_float4(sspf(acc[j]), sspf(acc[j + 1]),
                             sspf(acc[j + 2]), sspf(acc[j + 3]));
      *(float4*)(tr + half * 32 + j) = o;
    }
  }
}

// h += t @ W3 + b3
__global__ __launch_bounds__(256, 2) void update2_k(
    const float* __restrict__ t, const float* __restrict__ W3,
    const float* __restrict__ b3, float* __restrict__ h, int n) {
  int node = blockIdx.x * 256 + threadIdx.x;
  if (node >= n) return;
  const float* row = t + ((size_t)node << 6);
  float* hr = h + ((size_t)node << 6);
#pragma unroll
  for (int half = 0; half < 2; ++half) {
    const float* Wh = W3 + half * 32;
    float acc[32];
#pragma unroll
    for (int j = 0; j < 32; ++j) acc[j] = b3[half * 32 + j];
    for (int k = 0; k < HIDC; k += 4) {
      float4 rv = *(const float4*)(row + k);
      const float* w0 = Wh + (k + 0) * HIDC;
      const float* w1 = Wh + (k + 1) * HIDC;
      const float* w2 = Wh + (k + 2) * HIDC;
      const float* w3 = Wh + (k + 3) * HIDC;
#pragma unroll
      for (int j = 0; j < 32; ++j) {
        acc[j] = fmaf(rv.x, w0[j], acc[j]);
        acc[j] = fmaf(rv.y, w1[j], acc[j]);
        acc[j] = fmaf(rv.z, w2[j], acc[j]);
        acc[j] = fmaf(rv.w, w3[j], acc[j]);
      }
    }
#pragma unroll
    for (int j = 0; j < 32; j += 4) {
      float4 hv = *(float4*)(hr + half * 32 + j);
      hv.x += acc[j]; hv.y += acc[j + 1];
      hv.z += acc[j + 2]; hv.w += acc[j + 3];
      *(float4*)(hr + half * 32 + j) = hv;
    }
  }
}

// THE HOT KERNEL (R15-proven structure). One wave per dst node, unroll x4,
// register accumulator; 4-byte records, nearest-neighbor fp16 table, fp16 x.
__global__ __launch_bounds__(256) void gather_k(
    const int* __restrict__ rs, const int* __restrict__ er,
    const __half* __restrict__ tabh, const __half* __restrict__ x,
    float* __restrict__ agg, int n) {
  int j = threadIdx.x & 63;
  int node = (blockIdx.x * 256 + threadIdx.x) >> 6;
  if (node >= n) return;
  int beg = __builtin_amdgcn_readfirstlane(rs[node]);
  int end = __builtin_amdgcn_readfirstlane(rs[node + 1]);
  float acc = 0.0f;
  int k = beg;
  for (; k + 4 <= end; k += 4) {
    int r0 = er[k + 0];
    int r1 = er[k + 1];
    int r2 = er[k + 2];
    int r3 = er[k + 3];
    float t0 = __half2float(tabh[(((size_t)((unsigned)r0 >> 17)) << 6) + j]);
    float t1 = __half2float(tabh[(((size_t)((unsigned)r1 >> 17)) << 6) + j]);
    float t2 = __half2float(tabh[(((size_t)((unsigned)r2 >> 17)) << 6) + j]);
    float t3 = __half2float(tabh[(((size_t)((unsigned)r3 >> 17)) << 6) + j]);
    float x0 = __half2float(x[((size_t)(r0 & 0x1FFFF) << 6) + j]);
    float x1 = __half2float(x[((size_t)(r1 & 0x1FFFF) << 6) + j]);
    float x2 = __half2float(x[((size_t)(r2 & 0x1FFFF) << 6) + j]);
    float x3 = __half2float(x[((size_t)(r3 & 0x1FFFF) << 6) + j]);
    acc = fmaf(x0, t0, acc);
    acc = fmaf(x1, t1, acc);
    acc = fmaf(x2, t2, acc);
    acc = fmaf(x3, t3, acc);
  }
  for (; k < end; ++k) {
    int r = er[k];
    float t = __half2float(tabh[(((size_t)((unsigned)r >> 17)) << 6) + j]);
    float xv = __half2float(x[((size_t)(r & 0x1FFFF) << 6) + j]);
    acc = fmaf(xv, t, acc);
  }
  agg[((size_t)node << 6) + j] = acc;
}

// per-atom output MLP + segmented wave reduce (batch sorted) + atomic
__global__ __launch_bounds__(256, 2) void out_kernel_k(
    const float* __restrict__ h, const int* __restrict__ batch,
    const float* __restrict__ ow1, const float* __restrict__ ob1,
    const float* __restrict__ ow2, const float* __restrict__ ob2,
    float* __restrict__ outg, int n) {
  int node = blockIdx.x * 256 + threadIdx.x;
  int lane = threadIdx.x & 63;
  bool valid = node < n;
  int b = batch[valid ? node : (n - 1)];
  float s = 0.0f;
  if (valid) {
    const float* row = h + ((size_t)node << 6);
    float acc[32];
#pragma unroll
    for (int j = 0; j < 32; ++j) acc[j] = ob1[j];
    for (int k = 0; k < HIDC; k += 4) {
      float4 rv = *(const float4*)(row + k);
      const float* w0 = ow1 + (k + 0) * 32;
      const float* w1 = ow1 + (k + 1) * 32;
      const float* w2 = ow1 + (k + 2) * 32;
      const float* w3 = ow1 + (k + 3) * 32;
#pragma unroll
      for (int j = 0; j < 32; ++j) {
        acc[j] = fmaf(rv.x, w0[j], acc[j]);
        acc[j] = fmaf(rv.y, w1[j], acc[j]);
        acc[j] = fmaf(rv.z, w2[j], acc[j]);
        acc[j] = fmaf(rv.w, w3[j], acc[j]);
      }
    }
    s = ob2[0];
#pragma unroll
    for (int j = 0; j < 32; ++j) s = fmaf(sspf(acc[j]), ow2[j], s);
  }
#pragma unroll
  for (int off = 1; off < 64; off <<= 1) {
    float so = __shfl_down(s, off);
    int bo = __shfl_down(b, off);
    if (lane + off < 64 && bo == b) s += so;
  }
  int bprev = __shfl_up(b, 1);
  bool head = (lane == 0) || (bprev != b);
  if (head && valid) unsafeAtomicAdd(&outg[b], s);
}

__global__ __launch_bounds__(256) void final_k(
    const float* __restrict__ outg, const float* __restrict__ fw,
    const float* __restrict__ fb, float* __restrict__ out, int g) {
  int i = blockIdx.x * blockDim.x + threadIdx.x;
  if (i < g) out[i] = fmaf(outg[i], fw[0], fb[0]);
}

extern "C" void kernel_launch(void* const* d_in, const int* in_sizes, int n_in,
                              void* d_out, int out_size, void* d_ws, size_t ws_size,
                              hipStream_t stream) {
  const int*   z      = (const int*)d_in[0];
  const float* pos    = (const float*)d_in[1];
  const int*   batch  = (const int*)d_in[2];
  const int*   ei     = (const int*)d_in[3];
  const float* emb    = (const float*)d_in[4];
  const float* out_w1 = (const float*)d_in[5];
  const float* out_b1 = (const float*)d_in[6];
  const float* out_w2 = (const float*)d_in[7];
  const float* out_b2 = (const float*)d_in[8];
  const float* fin_w  = (const float*)d_in[9];
  const float* fin_b  = (const float*)d_in[10];
  const float* mlp_w1 = (const float*)d_in[11];
  const float* mlp_b1 = (const float*)d_in[12];
  const float* mlp_w2 = (const float*)d_in[13];
  const float* mlp_b2 = (const float*)d_in[14];
  const float* cf1    = (const float*)d_in[15];
  const float* cf2    = (const float*)d_in[16];
  const float* cf2b   = (const float*)d_in[17];
  const float* intw   = (const float*)d_in[18];
  const float* intb   = (const float*)d_in[19];

  const int N = in_sizes[0];
  const int E = in_sizes[3] / 2;
  const int G = out_size;
  const int NBUCK = (N + BSTRIDE - 1) / BSTRIDE;
  const int NCHUNK = (E + CHUNK_E - 1) / CHUNK_E;
  const int TPB = (N + 255) / 256;

  char* wsb = (char*)d_ws;
  size_t off = 0;
  auto alloc = [&](size_t bytes) { char* p = wsb + off; off += (bytes + 255) & ~(size_t)255; return p; };
  float*   h     = (float*)alloc((size_t)N * HIDC * sizeof(float));
  __half*  x     = (__half*)alloc((size_t)N * HIDC * sizeof(__half));
  float*   agg   = (float*)alloc((size_t)N * HIDC * sizeof(float));
  float*   tbuf  = (float*)alloc((size_t)N * HIDC * sizeof(float));
  __half*  tabh  = (__half*)alloc((size_t)NLAYER * TGRID * HIDC * sizeof(__half));
  int2*    er    = (int2*)alloc((size_t)E * sizeof(int2));   // bucket-ordered
  int*     er2   = (int*)alloc((size_t)E * sizeof(int));     // node-CSR, 4B packed
  int*     rs    = (int*)alloc((size_t)(N + 1) * sizeof(int));
  int*     bcnt  = (int*)alloc((size_t)MAXBUCK * sizeof(int));
  int*     boff  = (int*)alloc((size_t)MAXBUCK * sizeof(int));
  int*     chist = (int*)alloc((size_t)NCHUNK * MAXBUCK * sizeof(int));
  int*     cbase = (int*)alloc((size_t)NCHUNK * MAXBUCK * sizeof(int));
  float*   outg  = (float*)alloc((size_t)G * sizeof(float));

  build_table_k<<<dim3(NLAYER * TGRID), dim3(64), 0, stream>>>(
      mlp_w1, mlp_b1, mlp_w2, mlp_b2, tabh);
  hipMemsetAsync(outg, 0, (size_t)G * sizeof(float), stream);
  chist_k<<<dim3(NCHUNK), dim3(256), 0, stream>>>(ei + E, chist, E, NBUCK);
  csum_k<<<dim3((NBUCK + 255) / 256), dim3(256), 0, stream>>>(
      chist, bcnt, NCHUNK, NBUCK);
  bscan_k<<<dim3(1), dim3(256), 0, stream>>>(bcnt, boff, NBUCK);
  cbase_k<<<dim3(NBUCK), dim3(256), 0, stream>>>(chist, boff, cbase, NCHUNK);
  cstage_k<<<dim3(NCHUNK), dim3(256), 0, stream>>>(
      ei, pos, chist, cbase, er, E, NBUCK);
  bsort_k<<<dim3(NBUCK), dim3(256), 0, stream>>>(boff, bcnt, er, er2, rs, N);
  init_h_k<<<dim3((N * HIDC + 255) / 256), dim3(256), 0, stream>>>(z, emb, h, N * HIDC);

  const int gather_blocks = (N + 3) / 4;   // one wave per node
  for (int l = 0; l < NLAYER; ++l) {
    node_lin_k<<<dim3(TPB), dim3(256), 0, stream>>>(
        h, cf1 + (size_t)l * HIDC * HIDC, x, N);
    gather_k<<<dim3(gather_blocks), dim3(256), 0, stream>>>(
        rs, er2, tabh + (size_t)l * TGRID * HIDC, x, agg, N);
    update1_k<<<dim3(TPB), dim3(256), 0, stream>>>(
        agg, cf2 + (size_t)l * HIDC * HIDC, cf2b + l * HIDC, tbuf, N);
    update2_k<<<dim3(TPB), dim3(256), 0, stream>>>(
        tbuf, intw + (size_t)l * HIDC * HIDC, intb + l * HIDC, h, N);
  }

  out_kernel_k<<<dim3(TPB), dim3(256), 0, stream>>>(
      h, batch, out_w1, out_b1, out_w2, out_b2, outg, N);
  final_k<<<dim3((G + 255) / 256), dim3(256), 0, stream>>>(
      outg, fin_w, fin_b, (float*)d_out, G);
}

// Round 18
// 913.540 us; speedup vs baseline: 1.1271x; 1.0348x over previous
//
#include <hip/hip_runtime.h>
#include <hip/hip_fp16.h>
#include <cstdint>
#include <cstddef>

#define HIDC   64
#define NGAUSS 50
#define NLAYER 3
#define TGRID  8192            // nearest-neighbor grid; d-err <= 6.1e-4; 1MB/layer fp16
#define BSTRIDE 128            // dst nodes per bucket
#define MAXBUCK 1024           // supports N <= 131072
#define CHUNK_E 6656           // edges per partition chunk (stage fits 64KB LDS)
#define CUTOFF_F 10.0f
#define LOG2_C 0.69314718055994530942f

__device__ __forceinline__ float sspf(float v) {
  return fmaxf(v, 0.0f) + log1pf(expf(-fabsf(v))) - LOG2_C;
}

// ---------------------------------------------------------------------------
// Per-layer fp16 lookup tables T_l(g,j) = [ssp(rbf(d)@w1+b1)@w2+b2]_j * C(d)
// ---------------------------------------------------------------------------
__global__ __launch_bounds__(64) void build_table_k(
    const float* __restrict__ mlp_w1, const float* __restrict__ mlp_b1,
    const float* __restrict__ mlp_w2, const float* __restrict__ mlp_b2,
    __half* __restrict__ tabh) {
  int pid = blockIdx.x;              // l*TGRID + g
  int l = pid / TGRID;
  int g = pid - l * TGRID;
  int j = threadIdx.x;
  float d = (float)g * (CUTOFF_F / (float)(TGRID - 1));
  __shared__ float rbf_s[NGAUSS];
  __shared__ float hid_s[HIDC];
  const float delta = CUTOFF_F / (float)(NGAUSS - 1);
  const float coeff = -0.5f / (delta * delta);
  if (j < NGAUSS) {
    float t = d - (float)j * delta;
    rbf_s[j] = expf(coeff * t * t);
  }
  __syncthreads();
  const float* w1 = mlp_w1 + (size_t)l * NGAUSS * HIDC;
  float acc = mlp_b1[l * HIDC + j];
#pragma unroll
  for (int k = 0; k < NGAUSS; ++k) acc = fmaf(rbf_s[k], w1[k * HIDC + j], acc);
  hid_s[j] = sspf(acc);
  __syncthreads();
  const float* w2 = mlp_w2 + (size_t)l * HIDC * HIDC;
  float acc2 = mlp_b2[l * HIDC + j];
#pragma unroll
  for (int m = 0; m < HIDC; ++m) acc2 = fmaf(hid_s[m], w2[m * HIDC + j], acc2);
  float C = 0.5f * (cosf(d * (3.14159265358979323846f / CUTOFF_F)) + 1.0f);
  tabh[(size_t)pid * HIDC + j] = __float2half(acc2 * C);
}

// ---------------------------------------------------------------------------
// Zero-global-atomic chunked partition into bucket regions
// ---------------------------------------------------------------------------
__global__ __launch_bounds__(256) void chist_k(
    const int* __restrict__ edst, int* __restrict__ chunk_hist,
    int E, int nbuck) {
  __shared__ int cnt[MAXBUCK];
  for (int i = threadIdx.x; i < MAXBUCK; i += 256) cnt[i] = 0;
  __syncthreads();
  int c = blockIdx.x;
  int e0 = c * CHUNK_E;
  int e1 = e0 + CHUNK_E; if (e1 > E) e1 = E;
  for (int e = e0 + threadIdx.x; e < e1; e += 256)
    atomicAdd(&cnt[edst[e] >> 7], 1);
  __syncthreads();
  for (int i = threadIdx.x; i < nbuck; i += 256)
    chunk_hist[c * MAXBUCK + i] = cnt[i];
}

__global__ __launch_bounds__(256) void csum_k(
    const int* __restrict__ chunk_hist, int* __restrict__ bcnt,
    int nchunk, int nbuck) {
  int b = blockIdx.x * 256 + threadIdx.x;
  if (b >= nbuck) return;
  int s = 0;
  for (int c = 0; c < nchunk; ++c) s += chunk_hist[c * MAXBUCK + b];
  bcnt[b] = s;
}

__global__ __launch_bounds__(256) void bscan_k(
    const int* __restrict__ bcnt, int* __restrict__ boff, int nbuck) {
  __shared__ int sbuf[2][256];
  int tid = threadIdx.x;
  int base = tid * 4;
  int v0 = (base + 0 < nbuck) ? bcnt[base + 0] : 0;
  int v1 = (base + 1 < nbuck) ? bcnt[base + 1] : 0;
  int v2 = (base + 2 < nbuck) ? bcnt[base + 2] : 0;
  int v3 = (base + 3 < nbuck) ? bcnt[base + 3] : 0;
  int p0 = v0, p1 = p0 + v1, p2 = p1 + v2, p3 = p2 + v3;
  int pout = 0;
  sbuf[0][tid] = p3;
  __syncthreads();
  for (int off = 1; off < 256; off <<= 1) {
    int pin = pout; pout ^= 1;
    int v = sbuf[pin][tid];
    if (tid >= off) v += sbuf[pin][tid - off];
    sbuf[pout][tid] = v;
    __syncthreads();
  }
  int texc = sbuf[pout][tid] - p3;
  if (base + 0 < nbuck) boff[base + 0] = texc;
  if (base + 1 < nbuck) boff[base + 1] = texc + p0;
  if (base + 2 < nbuck) boff[base + 2] = texc + p1;
  if (base + 3 < nbuck) boff[base + 3] = texc + p2;
}

__global__ __launch_bounds__(256) void cbase_k(
    const int* __restrict__ chunk_hist, const int* __restrict__ boff,
    int* __restrict__ chunk_base, int nchunk) {
  __shared__ int sbuf[2][256];
  int b = blockIdx.x;
  int tid = threadIdx.x;
  int carry = 0;
  for (int t0 = 0; t0 < nchunk; t0 += 256) {
    int t = t0 + tid;
    int v = (t < nchunk) ? chunk_hist[(size_t)t * MAXBUCK + b] : 0;
    int pout = 0;
    sbuf[0][tid] = v;
    __syncthreads();
    for (int off = 1; off < 256; off <<= 1) {
      int pin = pout; pout ^= 1;
      int s = sbuf[pin][tid];
      if (tid >= off) s += sbuf[pin][tid - off];
      sbuf[pout][tid] = s;
      __syncthreads();
    }
    if (t < nchunk)
      chunk_base[(size_t)t * MAXBUCK + b] = boff[b] + carry + sbuf[pout][tid] - v;
    carry += sbuf[pout][255];
    __syncthreads();
  }
}

// LDS-staged scatter. SoA stage (2-way bank aliasing = free vs int2's 4-way);
// bucket id packed into stage_b's high bits so copy-out is element-parallel
// (all 256 lanes active; R17's per-bucket burst loop ran ~8/64 lanes).
__global__ __launch_bounds__(256) void cstage_k(
    const int* __restrict__ ei, const float* __restrict__ pos,
    const int* __restrict__ chunk_hist, const int* __restrict__ chunk_base,
    int2* __restrict__ er, int E, int nbuck) {
  __shared__ int stage_a[CHUNK_E];    // 26624 B
  __shared__ int stage_b[CHUNK_E];    // 26624 B
  __shared__ int loff[MAXBUCK];       // 4096 B
  __shared__ int lcur[MAXBUCK];       // 4096 B
  __shared__ int sbuf[2][256];        // 2048 B (total 63488 <= 64K)
  int c = blockIdx.x;
  int tid = threadIdx.x;
  const int* hrow = chunk_hist + (size_t)c * MAXBUCK;
  int base4 = tid * 4;
  int v0 = (base4 + 0 < nbuck) ? hrow[base4 + 0] : 0;
  int v1 = (base4 + 1 < nbuck) ? hrow[base4 + 1] : 0;
  int v2 = (base4 + 2 < nbuck) ? hrow[base4 + 2] : 0;
  int v3 = (base4 + 3 < nbuck) ? hrow[base4 + 3] : 0;
  int p0 = v0, p1 = p0 + v1, p2 = p1 + v2, p3 = p2 + v3;
  int pout = 0;
  sbuf[0][tid] = p3;
  __syncthreads();
  for (int off = 1; off < 256; off <<= 1) {
    int pin = pout; pout ^= 1;
    int v = sbuf[pin][tid];
    if (tid >= off) v += sbuf[pin][tid - off];
    sbuf[pout][tid] = v;
    __syncthreads();
  }
  int texc = sbuf[pout][tid] - p3;
  if (base4 + 0 < MAXBUCK) { loff[base4 + 0] = texc;      lcur[base4 + 0] = texc; }
  if (base4 + 1 < MAXBUCK) { loff[base4 + 1] = texc + p0; lcur[base4 + 1] = texc + p0; }
  if (base4 + 2 < MAXBUCK) { loff[base4 + 2] = texc + p1; lcur[base4 + 2] = texc + p1; }
  if (base4 + 3 < MAXBUCK) { loff[base4 + 3] = texc + p2; lcur[base4 + 3] = texc + p2; }
  __syncthreads();
  int e0 = c * CHUNK_E;
  int e1 = e0 + CHUNK_E; if (e1 > E) e1 = E;
  for (int e = e0 + tid; e < e1; e += 256) {
    int s = ei[e], t = ei[E + e];
    float dx = pos[3 * s + 0] - pos[3 * t + 0];
    float dy = pos[3 * s + 1] - pos[3 * t + 1];
    float dz = pos[3 * s + 2] - pos[3 * t + 2];
    float d = sqrtf(fmaf(dx, dx, fmaf(dy, dy, dz * dz)));
    float u = d * ((float)(TGRID - 1) / CUTOFF_F);
    int i0 = (int)(u + 0.5f);          // nearest
    if (i0 > TGRID - 1) i0 = TGRID - 1;
    int b = t >> 7;
    int dl = t & 127;
    int p = atomicAdd(&lcur[b], 1);
    stage_a[p] = s | (dl << 20);
    stage_b[p] = i0 | (b << 13);       // i0 is 13 bits (TGRID=8192)
  }
  __syncthreads();
  int total = e1 - e0;
  for (int i = tid; i < total; i += 256) {
    int sb = stage_b[i];
    int b = sb >> 13;
    int gb = chunk_base[(size_t)c * MAXBUCK + b];   // cached; near-sorted over lanes
    er[gb + (i - loff[b])] = make_int2(stage_a[i], sb & 0x1FFF);
  }
}

// One WG per bucket: self-computed node-CSR (degrees + scan -> rs), place.
// Final records packed to 4 B: src(17) | i0(15)<<17.
__global__ __launch_bounds__(256) void bsort_k(
    const int* __restrict__ boff, const int* __restrict__ bcnt,
    const int2* __restrict__ er, int* __restrict__ er2,
    int* __restrict__ rs, int n) {
  __shared__ int dcnt[BSTRIDE];
  __shared__ int lcur[BSTRIDE];
  __shared__ int sc[2][BSTRIDE];
  int b = blockIdx.x;
  int node0 = b << 7;
  int nn = n - node0; if (nn > BSTRIDE) nn = BSTRIDE;
  int tid = threadIdx.x;
  if (tid < BSTRIDE) dcnt[tid] = 0;
  __syncthreads();
  int base = boff[b];
  int cnt = bcnt[b];
  for (int r = tid; r < cnt; r += 256)
    atomicAdd(&dcnt[(unsigned)er[base + r].x >> 20], 1);
  __syncthreads();
  int pout = 0;
  if (tid < BSTRIDE) sc[0][tid] = dcnt[tid];
  __syncthreads();
  for (int off = 1; off < BSTRIDE; off <<= 1) {
    int pin = pout; pout ^= 1;
    if (tid < BSTRIDE) {
      int v = sc[pin][tid];
      if (tid >= off) v += sc[pin][tid - off];
      sc[pout][tid] = v;
    }
    __syncthreads();
  }
  if (tid < BSTRIDE) {
    int start = base + sc[pout][tid] - dcnt[tid];
    lcur[tid] = start;
    if (tid < nn) rs[node0 + tid] = start;
  }
  if (tid == 0 && b == gridDim.x - 1) rs[n] = base + cnt;
  __syncthreads();
  for (int r = tid; r < cnt; r += 256) {
    int2 rec = er[base + r];
    int dl = (unsigned)rec.x >> 20;
    int p = atomicAdd(&lcur[dl], 1);
    er2[p] = (rec.x & 0x1FFFF) | (rec.y << 17);
  }
}

// h = emb[z]
__global__ __launch_bounds__(256) void init_h_k(
    const int* __restrict__ z, const float* __restrict__ emb,
    float* __restrict__ h, int n64) {
  int i = blockIdx.x * blockDim.x + threadIdx.x;
  if (i >= n64) return;
  h[i] = emb[(z[i >> 6] << 6) | (i & 63)];
}

// ---------------------------------------------------------------------------
// Thread-per-node GEMMs, 32 output channels per pass (acc[32] ~= 45 VGPRs):
// structurally immune to the allocator's low-VGPR spill heuristic (R16: the
// 64-wide in-place variant spilled at VGPR_Count=52 -> 99 MB scratch WRITE).
// ---------------------------------------------------------------------------

// x = half(h @ W) (no bias), fp16 output for the gather
__global__ __launch_bounds__(256, 2) void node_lin_k(
    const float* __restrict__ h, const float* __restrict__ W,
    __half* __restrict__ x, int n) {
  int node = blockIdx.x * 256 + threadIdx.x;
  if (node >= n) return;
  const float* row = h + ((size_t)node << 6);
  __half2* xr = (__half2*)(x + ((size_t)node << 6));
#pragma unroll
  for (int half = 0; half < 2; ++half) {
    const float* Wh = W + half * 32;
    float acc[32];
#pragma unroll
    for (int j = 0; j < 32; ++j) acc[j] = 0.0f;
    for (int k = 0; k < HIDC; k += 4) {
      float4 rv = *(const float4*)(row + k);
      const float* w0 = Wh + (k + 0) * HIDC;
      const float* w1 = Wh + (k + 1) * HIDC;
      const float* w2 = Wh + (k + 2) * HIDC;
      const float* w3 = Wh + (k + 3) * HIDC;
#pragma unroll
      for (int j = 0; j < 32; ++j) {
        acc[j] = fmaf(rv.x, w0[j], acc[j]);
        acc[j] = fmaf(rv.y, w1[j], acc[j]);
        acc[j] = fmaf(rv.z, w2[j], acc[j]);
        acc[j] = fmaf(rv.w, w3[j], acc[j]);
      }
    }
#pragma unroll
    for (int j = 0; j < 32; j += 2)
      xr[(half * 32 + j) >> 1] = __floats2half2_rn(acc[j], acc[j + 1]);
  }
}

// t = ssp(agg @ W2 + b2)  (separate output buffer — no in-place aliasing)
__global__ __launch_bounds__(256, 2) void update1_k(
    const float* __restrict__ agg, const float* __restrict__ W2,
    const float* __restrict__ b2, float* __restrict__ t, int n) {
  int node = blockIdx.x * 256 + threadIdx.x;
  if (node >= n) return;
  const float* row = agg + ((size_t)node << 6);
  float* tr = t + ((size_t)node << 6);
#pragma unroll
  for (int half = 0; half < 2; ++half) {
    const float* Wh = W2 + half * 32;
    float acc[32];
#pragma unroll
    for (int j = 0; j < 32; ++j) acc[j] = b2[half * 32 + j];
    for (int k = 0; k < HIDC; k += 4) {
      float4 rv = *(const float4*)(row + k);
      const float* w0 = Wh + (k + 0) * HIDC;
      const float* w1 = Wh + (k + 1) * HIDC;
      const float* w2 = Wh + (k + 2) * HIDC;
      const float* w3 = Wh + (k + 3) * HIDC;
#pragma unroll
      for (int j = 0; j < 32; ++j) {
        acc[j] = fmaf(rv.x, w0[j], acc[j]);
        acc[j] = fmaf(rv.y, w1[j], acc[j]);
        acc[j] = fmaf(rv.z, w2[j], acc[j]);
        acc[j] = fmaf(rv.w, w3[j], acc[j]);
      }
    }
#pragma unroll
    for (int j = 0; j < 32; j += 4) {
      float4 o = make_float4(sspf(acc[j]), sspf(acc[j + 1]),
                             sspf(acc[j + 2]), sspf(acc[j + 3]));
      *(float4*)(tr + half * 32 + j) = o;
    }
  }
}

// h += t @ W3 + b3
__global__ __launch_bounds__(256, 2) void update2_k(
    const float* __restrict__ t, const float* __restrict__ W3,
    const float* __restrict__ b3, float* __restrict__ h, int n) {
  int node = blockIdx.x * 256 + threadIdx.x;
  if (node >= n) return;
  const float* row = t + ((size_t)node << 6);
  float* hr = h + ((size_t)node << 6);
#pragma unroll
  for (int half = 0; half < 2; ++half) {
    const float* Wh = W3 + half * 32;
    float acc[32];
#pragma unroll
    for (int j = 0; j < 32; ++j) acc[j] = b3[half * 32 + j];
    for (int k = 0; k < HIDC; k += 4) {
      float4 rv = *(const float4*)(row + k);
      const float* w0 = Wh + (k + 0) * HIDC;
      const float* w1 = Wh + (k + 1) * HIDC;
      const float* w2 = Wh + (k + 2) * HIDC;
      const float* w3 = Wh + (k + 3) * HIDC;
#pragma unroll
      for (int j = 0; j < 32; ++j) {
        acc[j] = fmaf(rv.x, w0[j], acc[j]);
        acc[j] = fmaf(rv.y, w1[j], acc[j]);
        acc[j] = fmaf(rv.z, w2[j], acc[j]);
        acc[j] = fmaf(rv.w, w3[j], acc[j]);
      }
    }
#pragma unroll
    for (int j = 0; j < 32; j += 4) {
      float4 hv = *(float4*)(hr + half * 32 + j);
      hv.x += acc[j]; hv.y += acc[j + 1];
      hv.z += acc[j + 2]; hv.w += acc[j + 3];
      *(float4*)(hr + half * 32 + j) = hv;
    }
  }
}

// THE HOT KERNEL. One wave per dst node, unroll x4, register accumulator;
// 4-byte records, nearest-neighbor fp16 table, fp16 x.
__global__ __launch_bounds__(256) void gather_k(
    const int* __restrict__ rs, const int* __restrict__ er,
    const __half* __restrict__ tabh, const __half* __restrict__ x,
    float* __restrict__ agg, int n) {
  int j = threadIdx.x & 63;
  int node = (blockIdx.x * 256 + threadIdx.x) >> 6;
  if (node >= n) return;
  int beg = __builtin_amdgcn_readfirstlane(rs[node]);
  int end = __builtin_amdgcn_readfirstlane(rs[node + 1]);
  float acc = 0.0f;
  int k = beg;
  for (; k + 4 <= end; k += 4) {
    int r0 = er[k + 0];
    int r1 = er[k + 1];
    int r2 = er[k + 2];
    int r3 = er[k + 3];
    float t0 = __half2float(tabh[(((size_t)((unsigned)r0 >> 17)) << 6) + j]);
    float t1 = __half2float(tabh[(((size_t)((unsigned)r1 >> 17)) << 6) + j]);
    float t2 = __half2float(tabh[(((size_t)((unsigned)r2 >> 17)) << 6) + j]);
    float t3 = __half2float(tabh[(((size_t)((unsigned)r3 >> 17)) << 6) + j]);
    float x0 = __half2float(x[((size_t)(r0 & 0x1FFFF) << 6) + j]);
    float x1 = __half2float(x[((size_t)(r1 & 0x1FFFF) << 6) + j]);
    float x2 = __half2float(x[((size_t)(r2 & 0x1FFFF) << 6) + j]);
    float x3 = __half2float(x[((size_t)(r3 & 0x1FFFF) << 6) + j]);
    acc = fmaf(x0, t0, acc);
    acc = fmaf(x1, t1, acc);
    acc = fmaf(x2, t2, acc);
    acc = fmaf(x3, t3, acc);
  }
  for (; k < end; ++k) {
    int r = er[k];
    float t = __half2float(tabh[(((size_t)((unsigned)r >> 17)) << 6) + j]);
    float xv = __half2float(x[((size_t)(r & 0x1FFFF) << 6) + j]);
    acc = fmaf(xv, t, acc);
  }
  agg[((size_t)node << 6) + j] = acc;
}

// per-atom output MLP + segmented wave reduce (batch sorted) + atomic
__global__ __launch_bounds__(256, 2) void out_kernel_k(
    const float* __restrict__ h, const int* __restrict__ batch,
    const float* __restrict__ ow1, const float* __restrict__ ob1,
    const float* __restrict__ ow2, const float* __restrict__ ob2,
    float* __restrict__ outg, int n) {
  int node = blockIdx.x * 256 + threadIdx.x;
  int lane = threadIdx.x & 63;
  bool valid = node < n;
  int b = batch[valid ? node : (n - 1)];
  float s = 0.0f;
  if (valid) {
    const float* row = h + ((size_t)node << 6);
    float acc[32];
#pragma unroll
    for (int j = 0; j < 32; ++j) acc[j] = ob1[j];
    for (int k = 0; k < HIDC; k += 4) {
      float4 rv = *(const float4*)(row + k);
      const float* w0 = ow1 + (k + 0) * 32;
      const float* w1 = ow1 + (k + 1) * 32;
      const float* w2 = ow1 + (k + 2) * 32;
      const float* w3 = ow1 + (k + 3) * 32;
#pragma unroll
      for (int j = 0; j < 32; ++j) {
        acc[j] = fmaf(rv.x, w0[j], acc[j]);
        acc[j] = fmaf(rv.y, w1[j], acc[j]);
        acc[j] = fmaf(rv.z, w2[j], acc[j]);
        acc[j] = fmaf(rv.w, w3[j], acc[j]);
      }
    }
    s = ob2[0];
#pragma unroll
    for (int j = 0; j < 32; ++j) s = fmaf(sspf(acc[j]), ow2[j], s);
  }
#pragma unroll
  for (int off = 1; off < 64; off <<= 1) {
    float so = __shfl_down(s, off);
    int bo = __shfl_down(b, off);
    if (lane + off < 64 && bo == b) s += so;
  }
  int bprev = __shfl_up(b, 1);
  bool head = (lane == 0) || (bprev != b);
  if (head && valid) unsafeAtomicAdd(&outg[b], s);
}

__global__ __launch_bounds__(256) void final_k(
    const float* __restrict__ outg, const float* __restrict__ fw,
    const float* __restrict__ fb, float* __restrict__ out, int g) {
  int i = blockIdx.x * blockDim.x + threadIdx.x;
  if (i < g) out[i] = fmaf(outg[i], fw[0], fb[0]);
}

extern "C" void kernel_launch(void* const* d_in, const int* in_sizes, int n_in,
                              void* d_out, int out_size, void* d_ws, size_t ws_size,
                              hipStream_t stream) {
  const int*   z      = (const int*)d_in[0];
  const float* pos    = (const float*)d_in[1];
  const int*   batch  = (const int*)d_in[2];
  const int*   ei     = (const int*)d_in[3];
  const float* emb    = (const float*)d_in[4];
  const float* out_w1 = (const float*)d_in[5];
  const float* out_b1 = (const float*)d_in[6];
  const float* out_w2 = (const float*)d_in[7];
  const float* out_b2 = (const float*)d_in[8];
  const float* fin_w  = (const float*)d_in[9];
  const float* fin_b  = (const float*)d_in[10];
  const float* mlp_w1 = (const float*)d_in[11];
  const float* mlp_b1 = (const float*)d_in[12];
  const float* mlp_w2 = (const float*)d_in[13];
  const float* mlp_b2 = (const float*)d_in[14];
  const float* cf1    = (const float*)d_in[15];
  const float* cf2    = (const float*)d_in[16];
  const float* cf2b   = (const float*)d_in[17];
  const float* intw   = (const float*)d_in[18];
  const float* intb   = (const float*)d_in[19];

  const int N = in_sizes[0];
  const int E = in_sizes[3] / 2;
  const int G = out_size;
  const int NBUCK = (N + BSTRIDE - 1) / BSTRIDE;
  const int NCHUNK = (E + CHUNK_E - 1) / CHUNK_E;
  const int TPB = (N + 255) / 256;

  char* wsb = (char*)d_ws;
  size_t off = 0;
  auto alloc = [&](size_t bytes) { char* p = wsb + off; off += (bytes + 255) & ~(size_t)255; return p; };
  float*   h     = (float*)alloc((size_t)N * HIDC * sizeof(float));
  __half*  x     = (__half*)alloc((size_t)N * HIDC * sizeof(__half));
  float*   agg   = (float*)alloc((size_t)N * HIDC * sizeof(float));
  float*   tbuf  = (float*)alloc((size_t)N * HIDC * sizeof(float));
  __half*  tabh  = (__half*)alloc((size_t)NLAYER * TGRID * HIDC * sizeof(__half));
  int2*    er    = (int2*)alloc((size_t)E * sizeof(int2));   // bucket-ordered
  int*     er2   = (int*)alloc((size_t)E * sizeof(int));     // node-CSR, 4B packed
  int*     rs    = (int*)alloc((size_t)(N + 1) * sizeof(int));
  int*     bcnt  = (int*)alloc((size_t)MAXBUCK * sizeof(int));
  int*     boff  = (int*)alloc((size_t)MAXBUCK * sizeof(int));
  int*     chist = (int*)alloc((size_t)NCHUNK * MAXBUCK * sizeof(int));
  int*     cbase = (int*)alloc((size_t)NCHUNK * MAXBUCK * sizeof(int));
  float*   outg  = (float*)alloc((size_t)G * sizeof(float));

  build_table_k<<<dim3(NLAYER * TGRID), dim3(64), 0, stream>>>(
      mlp_w1, mlp_b1, mlp_w2, mlp_b2, tabh);
  hipMemsetAsync(outg, 0, (size_t)G * sizeof(float), stream);
  chist_k<<<dim3(NCHUNK), dim3(256), 0, stream>>>(ei + E, chist, E, NBUCK);
  csum_k<<<dim3((NBUCK + 255) / 256), dim3(256), 0, stream>>>(
      chist, bcnt, NCHUNK, NBUCK);
  bscan_k<<<dim3(1), dim3(256), 0, stream>>>(bcnt, boff, NBUCK);
  cbase_k<<<dim3(NBUCK), dim3(256), 0, stream>>>(chist, boff, cbase, NCHUNK);
  cstage_k<<<dim3(NCHUNK), dim3(256), 0, stream>>>(
      ei, pos, chist, cbase, er, E, NBUCK);
  bsort_k<<<dim3(NBUCK), dim3(256), 0, stream>>>(boff, bcnt, er, er2, rs, N);
  init_h_k<<<dim3((N * HIDC + 255) / 256), dim3(256), 0, stream>>>(z, emb, h, N * HIDC);

  const int gather_blocks = (N + 3) / 4;   // one wave per node
  for (int l = 0; l < NLAYER; ++l) {
    node_lin_k<<<dim3(TPB), dim3(256), 0, stream>>>(
        h, cf1 + (size_t)l * HIDC * HIDC, x, N);
    gather_k<<<dim3(gather_blocks), dim3(256), 0, stream>>>(
        rs, er2, tabh + (size_t)l * TGRID * HIDC, x, agg, N);
    update1_k<<<dim3(TPB), dim3(256), 0, stream>>>(
        agg, cf2 + (size_t)l * HIDC * HIDC, cf2b + l * HIDC, tbuf, N);
    update2_k<<<dim3(TPB), dim3(256), 0, stream>>>(
        tbuf, intw + (size_t)l * HIDC * HIDC, intb + l * HIDC, h, N);
  }

  out_kernel_k<<<dim3(TPB), dim3(256), 0, stream>>>(
      h, batch, out_w1, out_b1, out_w2, out_b2, outg, N);
  final_k<<<dim3((G + 255) / 256), dim3(256), 0, stream>>>(
      outg, fin_w, fin_b, (float*)d_out, G);
}